// Round 3
// baseline (541.588 us; speedup 1.0000x reference)
//
#include <hip/hip_runtime.h>
#include <hip/hip_bf16.h>
#include <cmath>

#define HDIM 2048
#define NEXP 16
#define IDIM 512
#define ISDIM 2048
#define NTOK 2048
#define MAXTILES 80
#define ROWSCAP (MAXTILES * 64)

#define GU_NBLK_EXP (MAXTILES * 4)              // 64x128 tiles over experts
#define GU_NBLK_SH ((NTOK / 64) * (ISDIM / 128))  // 512
#define DN_NBLK_EXP (MAXTILES * 8)              // 64x256 tiles, N=2048
#define DN_NBLK_SH ((NTOK / 64) * (HDIM / 256))   // 256

typedef short bf16x8 __attribute__((ext_vector_type(8)));
typedef float f32x4 __attribute__((ext_vector_type(4)));
typedef unsigned short us;
typedef __attribute__((address_space(1))) const unsigned int* as1p;
typedef __attribute__((address_space(3))) unsigned int* as3p;

__device__ __forceinline__ us f2bf(float f) {
  unsigned int u = __builtin_bit_cast(unsigned int, f);
  u += 0x7FFFu + ((u >> 16) & 1u);
  return (us)(u >> 16);
}

// async 16B/lane global->LDS; lds base wave-uniform, HW adds lane*16
__device__ __forceinline__ void glds16(const void* g, void* l) {
  __builtin_amdgcn_global_load_lds((as1p)(unsigned long long)g,
                                   (as3p)(unsigned int)(unsigned long long)l, 16, 0, 0);
}

// ---------------- kernel 0: weights fp32 -> bf16 (row-major) --------------
struct SrcPtrs { const float* p[6]; };
__global__ __launch_bounds__(256) void k_convert(SrcPtrs s, us* __restrict__ dst) {
  int b = blockIdx.x;
  const float* sp;
  long long rel;
  size_t doff;
  if (b < 8192)       { sp = s.p[0]; rel = b;         doff = 0; }
  else if (b < 16384) { sp = s.p[1]; rel = b - 8192;  doff = 16777216; }
  else if (b < 24576) { sp = s.p[2]; rel = b - 16384; doff = 33554432; }
  else if (b < 26624) { sp = s.p[3]; rel = b - 24576; doff = 50331648; }
  else if (b < 28672) { sp = s.p[4]; rel = b - 26624; doff = 54525952; }
  else                { sp = s.p[5]; rel = b - 28672; doff = 58720256; }
  size_t i8 = (size_t)rel * 2048 + threadIdx.x * 8;
  float4 a = ((const float4*)sp)[i8 >> 2];
  float4 c = ((const float4*)sp)[(i8 >> 2) + 1];
  bf16x8 v = {(short)f2bf(a.x), (short)f2bf(a.y), (short)f2bf(a.z), (short)f2bf(a.w),
              (short)f2bf(c.x), (short)f2bf(c.y), (short)f2bf(c.z), (short)f2bf(c.w)};
  *(bf16x8*)(dst + doff + i8) = v;
}

// ------- kernel 1: router (wave per token) + x->bf16 conversion fused -----
__global__ __launch_bounds__(256) void k_router(const float* __restrict__ x,
                                                const float* __restrict__ gate_w,
                                                const float* __restrict__ sgw,
                                                us* __restrict__ xb,
                                                int* __restrict__ sel,
                                                float* __restrict__ wnorm,
                                                float* __restrict__ sig,
                                                int* __restrict__ counts) {
  __shared__ float lg[4][17];
  int tid = threadIdx.x, wid = tid >> 6, lane = tid & 63;
  int t = blockIdx.x * 4 + wid;
  const float4* xrow = reinterpret_cast<const float4*>(x + (size_t)t * HDIM);
  float4 xv[8];
#pragma unroll
  for (int s = 0; s < 8; s++) xv[s] = xrow[s * 64 + lane];
  ushort4* xbrow = reinterpret_cast<ushort4*>(xb + (size_t)t * HDIM);
#pragma unroll
  for (int s = 0; s < 8; s++) {
    ushort4 o;
    o.x = f2bf(xv[s].x); o.y = f2bf(xv[s].y); o.z = f2bf(xv[s].z); o.w = f2bf(xv[s].w);
    xbrow[s * 64 + lane] = o;
  }
#pragma unroll 1
  for (int e = 0; e < 17; e++) {
    const float4* gr =
        reinterpret_cast<const float4*>(e < 16 ? gate_w + (size_t)e * HDIM : sgw);
    float acc = 0.f;
#pragma unroll
    for (int s = 0; s < 8; s++) {
      float4 g = gr[s * 64 + lane];
      acc += xv[s].x * g.x + xv[s].y * g.y + xv[s].z * g.z + xv[s].w * g.w;
    }
#pragma unroll
    for (int off = 32; off; off >>= 1) acc += __shfl_xor(acc, off, 64);
    if (lane == 0) lg[wid][e] = acc;
  }
  if (lane == 0) {
    float* L = lg[wid];
    int i1 = 0; float v1 = L[0];
    for (int i = 1; i < NEXP; i++) if (L[i] > v1) { v1 = L[i]; i1 = i; }
    int i2 = (i1 == 0) ? 1 : 0; float v2 = L[i2];
    for (int i = 0; i < NEXP; i++)
      if (i != i1 && i != i2 && L[i] > v2) { v2 = L[i]; i2 = i; }
    float wa = 1.f / (1.f + expf(v2 - v1));  // renorm top-2 softmax
    sel[2 * t] = i1; sel[2 * t + 1] = i2;
    wnorm[2 * t] = wa; wnorm[2 * t + 1] = 1.f - wa;
    sig[t] = 1.f / (1.f + expf(-L[16]));
    atomicAdd(&counts[i1], 1);
    atomicAdd(&counts[i2], 1);
  }
}

// ------- kernel 2: scan + scatter in a single block -----------------------
__global__ __launch_bounds__(256) void k_scan_scatter(const int* __restrict__ counts,
                                                      const int* __restrict__ sel,
                                                      const float* __restrict__ wnorm,
                                                      int* __restrict__ tile_expert,
                                                      int* __restrict__ row_token,
                                                      float* __restrict__ rw) {
  __shared__ int offs_s[NEXP];
  __shared__ int fill_s[NEXP];
  int tid = threadIdx.x;
  for (int r = tid; r < ROWSCAP; r += 256) row_token[r] = -1;
  if (tid < NEXP) fill_s[tid] = 0;
  if (tid == 0) {
    int acc = 0;
    for (int e = 0; e < NEXP; e++) {
      offs_s[e] = acc;
      int nt = (counts[e] + 63) >> 6;
      for (int i = 0; i < nt; i++) tile_expert[(acc >> 6) + i] = e;
      acc += nt << 6;
    }
    for (int m = acc >> 6; m < MAXTILES; m++) tile_expert[m] = -1;
  }
  __syncthreads();
  for (int t = tid; t < NTOK; t += 256) {
    for (int k = 0; k < 2; k++) {
      int e = sel[2 * t + k];
      int pos = atomicAdd(&fill_s[e], 1);
      int row = offs_s[e] + pos;
      row_token[row] = t;
      rw[row] = wnorm[2 * t + k];
    }
  }
}

// ------- kernel 3: fused gate/up GEMM (experts + shared), 64x128 tiles ----
// LDS layout (glds-compatible, xor-swizzled): slot(r,c) = r*8 + (c ^ (r&7)),
// each slot 16B (8 bf16 of k-chunk c). Fragment ds_read_b128 lands 2-way.
__global__ __launch_bounds__(256) void k_gu(
    const us* __restrict__ xb, const us* __restrict__ wb1, const us* __restrict__ wb3,
    const us* __restrict__ wsgb, const us* __restrict__ wsub,
    const int* __restrict__ tile_expert, const int* __restrict__ row_token,
    us* __restrict__ hmid, us* __restrict__ hs) {
  __shared__ us As[64 * 64];    // 8KB
  __shared__ us Bg[128 * 64];   // 16KB
  __shared__ us Bu[128 * 64];   // 16KB
  int bid = blockIdx.x, tid = threadIdx.x;
  int w = tid >> 6, lane = tid & 63;
  const us *bG, *bU;
  us* outp;
  int mt, n0, ostride, tok0, tok1;
  int r0 = tid >> 3;  // A row slot (phase 0), phase 1 = +32
  if (bid < GU_NBLK_EXP) {
    mt = bid >> 2; int nt = bid & 3;
    int e = tile_expert[mt];
    if (e < 0) return;
    int a = row_token[mt * 64 + r0];
    int b = row_token[mt * 64 + r0 + 32];
    tok0 = a < 0 ? 0 : a;
    tok1 = b < 0 ? 0 : b;
    bG = wb1 + ((size_t)e * IDIM + nt * 128) * HDIM;
    bU = wb3 + ((size_t)e * IDIM + nt * 128) * HDIM;
    outp = hmid; ostride = IDIM; n0 = nt * 128;
  } else {
    int sb = bid - GU_NBLK_EXP;
    mt = sb >> 4; int nt = sb & 15;
    tok0 = mt * 64 + r0;
    tok1 = tok0 + 32;
    bG = wsgb + (size_t)(nt * 128) * HDIM;
    bU = wsub + (size_t)(nt * 128) * HDIM;
    outp = hs; ostride = ISDIM; n0 = nt * 128;
  }
  int quad = lane >> 4, l16 = lane & 15, sw = l16 & 7;
  int cg = ((lane & 7) ^ (lane >> 3)) * 8;  // swizzled k-chunk (elem offset)
  const us* aSrc0 = xb + (size_t)tok0 * HDIM + ((tid & 7) ^ (r0 & 7)) * 8;
  const us* aSrc1 = xb + (size_t)tok1 * HDIM + ((tid & 7) ^ (r0 & 7)) * 8;
  size_t bLaneOff = (size_t)(lane >> 3) * HDIM + cg;
  f32x4 accG[4][2] = {};
  f32x4 accU[4][2] = {};
  for (int k0 = 0; k0 < HDIM; k0 += 64) {
    // A: manual 16B copy (already bf16), swizzled slots
    ((bf16x8*)As)[tid] = *(const bf16x8*)(aSrc0 + k0);
    ((bf16x8*)As)[tid + 256] = *(const bf16x8*)(aSrc1 + k0);
    // B: 32 glds instrs (16 per matrix), 8 per wave
#pragma unroll
    for (int ii = 0; ii < 8; ii++) {
      int i = w * 8 + ii;
      int g = i & 15;
      if (i < 16)
        glds16(bG + (size_t)g * 8 * HDIM + bLaneOff + k0, &Bg[g * 64 * 8]);
      else
        glds16(bU + (size_t)g * 8 * HDIM + bLaneOff + k0, &Bu[g * 64 * 8]);
    }
    __syncthreads();
#pragma unroll
    for (int ks = 0; ks < 2; ks++) {
      int cb = (ks * 4 + quad) ^ sw;
      bf16x8 af[4], bg[2], bu[2];
#pragma unroll
      for (int ms = 0; ms < 4; ms++)
        af[ms] = *(const bf16x8*)&As[((ms * 16 + l16) * 8 + cb) * 8];
#pragma unroll
      for (int ns = 0; ns < 2; ns++) {
        int n = w * 32 + ns * 16 + l16;
        bg[ns] = *(const bf16x8*)&Bg[(n * 8 + cb) * 8];
        bu[ns] = *(const bf16x8*)&Bu[(n * 8 + cb) * 8];
      }
#pragma unroll
      for (int ms = 0; ms < 4; ms++)
#pragma unroll
        for (int ns = 0; ns < 2; ns++) {
          accG[ms][ns] = __builtin_amdgcn_mfma_f32_16x16x32_bf16(af[ms], bg[ns], accG[ms][ns], 0, 0, 0);
          accU[ms][ns] = __builtin_amdgcn_mfma_f32_16x16x32_bf16(af[ms], bu[ns], accU[ms][ns], 0, 0, 0);
        }
    }
    __syncthreads();
  }
#pragma unroll
  for (int ms = 0; ms < 4; ms++)
#pragma unroll
    for (int ns = 0; ns < 2; ns++)
#pragma unroll
      for (int r = 0; r < 4; r++) {
        float g = accG[ms][ns][r], u = accU[ms][ns][r];
        float hv = (g / (1.f + __expf(-g))) * u;
        int row = mt * 64 + ms * 16 + quad * 4 + r;
        int col = n0 + w * 32 + ns * 16 + l16;
        outp[(size_t)row * ostride + col] = f2bf(hv);
      }
}

// ------- kernel 4: fused down GEMMs + weighted atomic combine into out ----
__global__ __launch_bounds__(256) void k_down(
    const us* __restrict__ hmid, const us* __restrict__ hs,
    const us* __restrict__ wb2, const us* __restrict__ wsdb,
    const int* __restrict__ tile_expert, const int* __restrict__ row_token,
    const float* __restrict__ rw, const float* __restrict__ sig,
    float* __restrict__ out) {
  __shared__ us As[64 * 64];    // 8KB
  __shared__ us Bs[256 * 64];   // 32KB
  __shared__ int rt_s[64];
  __shared__ float rw_s[64];
  int bid = blockIdx.x, tid = threadIdx.x;
  int w = tid >> 6, lane = tid & 63;
  const us *aBase, *bBase;
  int K, mt, n0;
  if (bid < DN_NBLK_EXP) {
    mt = bid >> 3; int nt = bid & 7;
    int e = tile_expert[mt];
    if (e < 0) return;
    aBase = hmid + (size_t)mt * 64 * IDIM; K = IDIM;
    bBase = wb2 + ((size_t)e * HDIM + nt * 256) * IDIM;
    n0 = nt * 256;
    if (tid < 64) {
      int tk = row_token[mt * 64 + tid];
      rt_s[tid] = tk;
      rw_s[tid] = tk < 0 ? 0.f : rw[mt * 64 + tid];
    }
  } else {
    int sb = bid - DN_NBLK_EXP;
    mt = sb >> 3; int nt = sb & 7;
    aBase = hs + (size_t)mt * 64 * ISDIM; K = ISDIM;
    bBase = wsdb + (size_t)(nt * 256) * ISDIM;
    n0 = nt * 256;
    if (tid < 64) {
      rt_s[tid] = mt * 64 + tid;
      rw_s[tid] = sig[mt * 64 + tid];
    }
  }
  int quad = lane >> 4, l16 = lane & 15, sw = l16 & 7;
  int r0 = tid >> 3;
  int cg = ((lane & 7) ^ (lane >> 3)) * 8;
  const us* aSrc0 = aBase + (size_t)r0 * K + ((tid & 7) ^ (r0 & 7)) * 8;
  const us* aSrc1 = aBase + (size_t)(r0 + 32) * K + ((tid & 7) ^ (r0 & 7)) * 8;
  size_t bLaneOff = (size_t)(lane >> 3) * K + cg;
  f32x4 acc[4][4] = {};
  for (int k0 = 0; k0 < K; k0 += 64) {
    ((bf16x8*)As)[tid] = *(const bf16x8*)(aSrc0 + k0);
    ((bf16x8*)As)[tid + 256] = *(const bf16x8*)(aSrc1 + k0);
#pragma unroll
    for (int ii = 0; ii < 8; ii++) {
      int g = w * 8 + ii;  // 0..31
      glds16(bBase + (size_t)g * 8 * K + bLaneOff + k0, &Bs[g * 64 * 8]);
    }
    __syncthreads();
#pragma unroll
    for (int ks = 0; ks < 2; ks++) {
      int cb = (ks * 4 + quad) ^ sw;
      bf16x8 af[4], bf[4];
#pragma unroll
      for (int ms = 0; ms < 4; ms++)
        af[ms] = *(const bf16x8*)&As[((ms * 16 + l16) * 8 + cb) * 8];
#pragma unroll
      for (int ns = 0; ns < 4; ns++) {
        int n = w * 64 + ns * 16 + l16;
        bf[ns] = *(const bf16x8*)&Bs[(n * 8 + cb) * 8];
      }
#pragma unroll
      for (int ms = 0; ms < 4; ms++)
#pragma unroll
        for (int ns = 0; ns < 4; ns++)
          acc[ms][ns] = __builtin_amdgcn_mfma_f32_16x16x32_bf16(af[ms], bf[ns], acc[ms][ns], 0, 0, 0);
    }
    __syncthreads();
  }
#pragma unroll
  for (int ms = 0; ms < 4; ms++)
#pragma unroll
    for (int r = 0; r < 4; r++) {
      int rr = ms * 16 + quad * 4 + r;
      int tk = rt_s[rr];
      float wgt = rw_s[rr];
      if (tk >= 0) {
        float* orow = out + (size_t)tk * HDIM + n0 + w * 64;
#pragma unroll
        for (int ns = 0; ns < 4; ns++)
          atomicAdd(orow + ns * 16 + l16, wgt * acc[ms][ns][r]);
      }
    }
}

extern "C" void kernel_launch(void* const* d_in, const int* in_sizes, int n_in,
                              void* d_out, int out_size, void* d_ws, size_t ws_size,
                              hipStream_t stream) {
  const float* x = (const float*)d_in[0];
  const float* gate_w = (const float*)d_in[1];
  const float* w1 = (const float*)d_in[2];
  const float* w2 = (const float*)d_in[3];
  const float* w3 = (const float*)d_in[4];
  const float* wsg = (const float*)d_in[5];
  const float* wsu = (const float*)d_in[6];
  const float* wsd = (const float*)d_in[7];
  const float* sgw = (const float*)d_in[8];
  float* out = (float*)d_out;

  // workspace carve (16B aligned)
  us* xb = (us*)d_ws;                               // 4,194,304
  us* hs = xb + (size_t)NTOK * HDIM;                // 4,194,304
  us* hmid = hs + (size_t)NTOK * ISDIM;             // 2,621,440
  us* wb1 = hmid + (size_t)ROWSCAP * IDIM;          // 16,777,216
  us* wb3 = wb1 + (size_t)16777216;                 // 16,777,216
  us* wb2 = wb3 + (size_t)16777216;                 // 16,777,216
  us* wsgb = wb2 + (size_t)16777216;                // 4,194,304
  us* wsub = wsgb + (size_t)4194304;                // 4,194,304
  us* wsdb = wsub + (size_t)4194304;                // 4,194,304
  float* rw = (float*)(wsdb + (size_t)4194304);     // ROWSCAP
  float* wnorm = rw + ROWSCAP;                      // 4096
  float* sig = wnorm + 2 * NTOK;                    // 2048
  int* sel = (int*)(sig + NTOK);                    // 4096
  int* row_token = sel + 2 * NTOK;                  // ROWSCAP
  int* counts = row_token + ROWSCAP;                // 16
  int* tile_expert = counts + NEXP;                 // 80

  SrcPtrs sp;
  sp.p[0] = w1; sp.p[1] = w3; sp.p[2] = w2;
  sp.p[3] = wsg; sp.p[4] = wsu; sp.p[5] = wsd;

  hipMemsetAsync(counts, 0, NEXP * sizeof(int), stream);
  hipMemsetAsync(out, 0, (size_t)out_size * sizeof(float), stream);
  k_convert<<<dim3(30720), dim3(256), 0, stream>>>(sp, wb1);
  k_router<<<dim3(NTOK / 4), dim3(256), 0, stream>>>(x, gate_w, sgw, xb, sel, wnorm,
                                                     sig, counts);
  k_scan_scatter<<<dim3(1), dim3(256), 0, stream>>>(counts, sel, wnorm, tile_expert,
                                                    row_token, rw);
  k_gu<<<dim3(GU_NBLK_EXP + GU_NBLK_SH), dim3(256), 0, stream>>>(
      xb, wb1, wb3, wsgb, wsub, tile_expert, row_token, hmid, hs);
  k_down<<<dim3(DN_NBLK_EXP + DN_NBLK_SH), dim3(256), 0, stream>>>(
      hmid, hs, wb2, wsdb, tile_expert, row_token, rw, sig, out);
}

// Round 4
// 512.950 us; speedup vs baseline: 1.0558x; 1.0558x over previous
//
#include <hip/hip_runtime.h>
#include <hip/hip_bf16.h>
#include <cmath>

#define HDIM 2048
#define NEXP 16
#define IDIM 512
#define ISDIM 2048
#define NTOK 2048
#define MAXTILES 80
#define ROWSCAP (MAXTILES * 64)

#define GU_NBLK_EXP (MAXTILES * 4)                // 64x128 tiles over experts
#define GU_NBLK_SH ((NTOK / 64) * (ISDIM / 128))  // 512
#define DN_NBLK_EXP (MAXTILES * 8)                // 64x256 tiles, N=2048
#define DN_NBLK_SH ((NTOK / 64) * (HDIM / 256))   // 256

typedef short bf16x8 __attribute__((ext_vector_type(8)));
typedef float f32x4 __attribute__((ext_vector_type(4)));
typedef unsigned short us;
typedef __attribute__((address_space(1))) const unsigned int* as1p;
typedef __attribute__((address_space(3))) unsigned int* as3p;

__device__ __forceinline__ us f2bf(float f) {
  unsigned int u = __builtin_bit_cast(unsigned int, f);
  u += 0x7FFFu + ((u >> 16) & 1u);
  return (us)(u >> 16);
}

// async 16B/lane global->LDS; global vaddr may be per-lane, LDS base wave-uniform
__device__ __forceinline__ void glds16(const void* g, void* l) {
  __builtin_amdgcn_global_load_lds((as1p)(unsigned long long)g,
                                   (as3p)(unsigned int)(unsigned long long)l, 16, 0, 0);
}

// ---------------- kernel 0: weights fp32 -> bf16 (row-major) --------------
struct SrcPtrs { const float* p[6]; };
__global__ __launch_bounds__(256) void k_convert(SrcPtrs s, us* __restrict__ dst) {
  int b = blockIdx.x;
  const float* sp;
  long long rel;
  size_t doff;
  if (b < 8192)       { sp = s.p[0]; rel = b;         doff = 0; }
  else if (b < 16384) { sp = s.p[1]; rel = b - 8192;  doff = 16777216; }
  else if (b < 24576) { sp = s.p[2]; rel = b - 16384; doff = 33554432; }
  else if (b < 26624) { sp = s.p[3]; rel = b - 24576; doff = 50331648; }
  else if (b < 28672) { sp = s.p[4]; rel = b - 26624; doff = 54525952; }
  else                { sp = s.p[5]; rel = b - 28672; doff = 58720256; }
  size_t i8 = (size_t)rel * 2048 + threadIdx.x * 8;
  float4 a = ((const float4*)sp)[i8 >> 2];
  float4 c = ((const float4*)sp)[(i8 >> 2) + 1];
  bf16x8 v = {(short)f2bf(a.x), (short)f2bf(a.y), (short)f2bf(a.z), (short)f2bf(a.w),
              (short)f2bf(c.x), (short)f2bf(c.y), (short)f2bf(c.z), (short)f2bf(c.w)};
  *(bf16x8*)(dst + doff + i8) = v;
}

// ------- kernel 1: router (wave per token) + x->bf16 conversion fused -----
__global__ __launch_bounds__(256) void k_router(const float* __restrict__ x,
                                                const float* __restrict__ gate_w,
                                                const float* __restrict__ sgw,
                                                us* __restrict__ xb,
                                                int* __restrict__ sel,
                                                float* __restrict__ wnorm,
                                                float* __restrict__ sig,
                                                int* __restrict__ counts) {
  __shared__ float lg[4][17];
  int tid = threadIdx.x, wid = tid >> 6, lane = tid & 63;
  int t = blockIdx.x * 4 + wid;
  const float4* xrow = reinterpret_cast<const float4*>(x + (size_t)t * HDIM);
  float4 xv[8];
#pragma unroll
  for (int s = 0; s < 8; s++) xv[s] = xrow[s * 64 + lane];
  ushort4* xbrow = reinterpret_cast<ushort4*>(xb + (size_t)t * HDIM);
#pragma unroll
  for (int s = 0; s < 8; s++) {
    ushort4 o;
    o.x = f2bf(xv[s].x); o.y = f2bf(xv[s].y); o.z = f2bf(xv[s].z); o.w = f2bf(xv[s].w);
    xbrow[s * 64 + lane] = o;
  }
#pragma unroll 1
  for (int e = 0; e < 17; e++) {
    const float4* gr =
        reinterpret_cast<const float4*>(e < 16 ? gate_w + (size_t)e * HDIM : sgw);
    float acc = 0.f;
#pragma unroll
    for (int s = 0; s < 8; s++) {
      float4 g = gr[s * 64 + lane];
      acc += xv[s].x * g.x + xv[s].y * g.y + xv[s].z * g.z + xv[s].w * g.w;
    }
#pragma unroll
    for (int off = 32; off; off >>= 1) acc += __shfl_xor(acc, off, 64);
    if (lane == 0) lg[wid][e] = acc;
  }
  if (lane == 0) {
    float* L = lg[wid];
    int i1 = 0; float v1 = L[0];
    for (int i = 1; i < NEXP; i++) if (L[i] > v1) { v1 = L[i]; i1 = i; }
    int i2 = (i1 == 0) ? 1 : 0; float v2 = L[i2];
    for (int i = 0; i < NEXP; i++)
      if (i != i1 && i != i2 && L[i] > v2) { v2 = L[i]; i2 = i; }
    float wa = 1.f / (1.f + expf(v2 - v1));  // renorm top-2 softmax
    sel[2 * t] = i1; sel[2 * t + 1] = i2;
    wnorm[2 * t] = wa; wnorm[2 * t + 1] = 1.f - wa;
    sig[t] = 1.f / (1.f + expf(-L[16]));
    atomicAdd(&counts[i1], 1);
    atomicAdd(&counts[i2], 1);
  }
}

// ------- kernel 2: scan + scatter in a single block -----------------------
__global__ __launch_bounds__(256) void k_scan_scatter(const int* __restrict__ counts,
                                                      const int* __restrict__ sel,
                                                      const float* __restrict__ wnorm,
                                                      int* __restrict__ tile_expert,
                                                      int* __restrict__ row_token,
                                                      int* __restrict__ rowk,
                                                      float* __restrict__ rw) {
  __shared__ int offs_s[NEXP];
  __shared__ int fill_s[NEXP];
  int tid = threadIdx.x;
  for (int r = tid; r < ROWSCAP; r += 256) row_token[r] = -1;
  if (tid < NEXP) fill_s[tid] = 0;
  if (tid == 0) {
    int acc = 0;
    for (int e = 0; e < NEXP; e++) {
      offs_s[e] = acc;
      int nt = (counts[e] + 63) >> 6;
      for (int i = 0; i < nt; i++) tile_expert[(acc >> 6) + i] = e;
      acc += nt << 6;
    }
    for (int m = acc >> 6; m < MAXTILES; m++) tile_expert[m] = -1;
  }
  __syncthreads();
  for (int t = tid; t < NTOK; t += 256) {
    for (int k = 0; k < 2; k++) {
      int e = sel[2 * t + k];
      int pos = atomicAdd(&fill_s[e], 1);
      int row = offs_s[e] + pos;
      row_token[row] = t;
      rowk[row] = k;
      rw[row] = wnorm[2 * t + k];
    }
  }
}

// ------- kernel 3: fused gate/up GEMM (experts + shared), 64x128 tiles ----
// LDS layout (glds-compatible, xor-swizzled): slot(r,c) = r*8 + (c ^ (r&7)),
// each slot 16B (8 bf16 of k-chunk c). Fragment ds_read_b128 lands conflict-free.
__global__ __launch_bounds__(256) void k_gu(
    const us* __restrict__ xb, const us* __restrict__ wb1, const us* __restrict__ wb3,
    const us* __restrict__ wsgb, const us* __restrict__ wsub,
    const int* __restrict__ tile_expert, const int* __restrict__ row_token,
    us* __restrict__ hmid, us* __restrict__ hs) {
  __shared__ us As[64 * 64];    // 8KB
  __shared__ us Bg[128 * 64];   // 16KB
  __shared__ us Bu[128 * 64];   // 16KB
  int bid = blockIdx.x, tid = threadIdx.x;
  int w = tid >> 6, lane = tid & 63;
  int lr = lane >> 3, lc = lane & 7;
  int arow0 = w * 16 + lr, arow1 = arow0 + 8;  // wave stages A rows w*16..w*16+15
  const us *bG, *bU;
  us* outp;
  int mt, n0, ostride, tok0, tok1;
  if (bid < GU_NBLK_EXP) {
    mt = bid >> 2; int nt = bid & 3;
    int e = tile_expert[mt];
    if (e < 0) return;
    int a = row_token[mt * 64 + arow0];
    int b = row_token[mt * 64 + arow1];
    tok0 = a < 0 ? 0 : a;
    tok1 = b < 0 ? 0 : b;
    bG = wb1 + ((size_t)e * IDIM + nt * 128) * HDIM;
    bU = wb3 + ((size_t)e * IDIM + nt * 128) * HDIM;
    outp = hmid; ostride = IDIM; n0 = nt * 128;
  } else {
    int sb = bid - GU_NBLK_EXP;
    mt = sb >> 4; int nt = sb & 15;
    tok0 = mt * 64 + arow0;
    tok1 = mt * 64 + arow1;
    bG = wsgb + (size_t)(nt * 128) * HDIM;
    bU = wsub + (size_t)(nt * 128) * HDIM;
    outp = hs; ostride = ISDIM; n0 = nt * 128;
  }
  int quad = lane >> 4, l16 = lane & 15, sw = l16 & 7;
  int swz = (lc ^ lr) * 8;  // pre-swizzled k-chunk for staging
  const us* aSrc0 = xb + (size_t)tok0 * HDIM + swz;
  const us* aSrc1 = xb + (size_t)tok1 * HDIM + swz;
  size_t bLaneOff = (size_t)lr * HDIM + swz;
  f32x4 accG[4][2] = {};
  f32x4 accU[4][2] = {};
  for (int k0 = 0; k0 < HDIM; k0 += 64) {
    // A: 2 glds per wave (gathered rows, per-lane global addresses)
    glds16(aSrc0 + k0, As + (size_t)(w * 2) * 512);
    glds16(aSrc1 + k0, As + (size_t)(w * 2 + 1) * 512);
    // B: 32 glds per block (16 per matrix), 8 per wave
#pragma unroll
    for (int ii = 0; ii < 8; ii++) {
      int i = w * 8 + ii;
      int g = i & 15;
      if (i < 16)
        glds16(bG + (size_t)g * 8 * HDIM + bLaneOff + k0, Bg + (size_t)g * 512);
      else
        glds16(bU + (size_t)g * 8 * HDIM + bLaneOff + k0, Bu + (size_t)g * 512);
    }
    __syncthreads();
#pragma unroll
    for (int ks = 0; ks < 2; ks++) {
      int cb = (ks * 4 + quad) ^ sw;
      bf16x8 af[4], bg[2], bu[2];
#pragma unroll
      for (int ms = 0; ms < 4; ms++)
        af[ms] = *(const bf16x8*)&As[((ms * 16 + l16) * 8 + cb) * 8];
#pragma unroll
      for (int ns = 0; ns < 2; ns++) {
        int n = w * 32 + ns * 16 + l16;
        bg[ns] = *(const bf16x8*)&Bg[(n * 8 + cb) * 8];
        bu[ns] = *(const bf16x8*)&Bu[(n * 8 + cb) * 8];
      }
#pragma unroll
      for (int ms = 0; ms < 4; ms++)
#pragma unroll
        for (int ns = 0; ns < 2; ns++) {
          accG[ms][ns] = __builtin_amdgcn_mfma_f32_16x16x32_bf16(af[ms], bg[ns], accG[ms][ns], 0, 0, 0);
          accU[ms][ns] = __builtin_amdgcn_mfma_f32_16x16x32_bf16(af[ms], bu[ns], accU[ms][ns], 0, 0, 0);
        }
    }
    __syncthreads();
  }
#pragma unroll
  for (int ms = 0; ms < 4; ms++)
#pragma unroll
    for (int ns = 0; ns < 2; ns++)
#pragma unroll
      for (int r = 0; r < 4; r++) {
        float g = accG[ms][ns][r], u = accU[ms][ns][r];
        float hv = (g / (1.f + __expf(-g))) * u;
        int row = mt * 64 + ms * 16 + quad * 4 + r;
        int col = n0 + w * 32 + ns * 16 + l16;
        outp[(size_t)row * ostride + col] = f2bf(hv);
      }
}

// ------- kernel 4: fused down GEMMs, weighted bf16 stores into slabs ------
// slab layout: [0]=slot0 (k=0 expert contrib), [1]=slot1 (k=1), [2]=sig*shared
__global__ __launch_bounds__(256) void k_down(
    const us* __restrict__ hmid, const us* __restrict__ hs,
    const us* __restrict__ wb2, const us* __restrict__ wsdb,
    const int* __restrict__ tile_expert, const int* __restrict__ row_token,
    const int* __restrict__ rowk, const float* __restrict__ rw,
    const float* __restrict__ sig, us* __restrict__ slab) {
  __shared__ us As[64 * 64];    // 8KB
  __shared__ us Bs[256 * 64];   // 32KB
  __shared__ long long idx_s[64];
  __shared__ float wgt_s[64];
  int bid = blockIdx.x, tid = threadIdx.x;
  int w = tid >> 6, lane = tid & 63;
  const us *aBase, *bBase;
  int K, mt, n0;
  if (bid < DN_NBLK_EXP) {
    mt = bid >> 3; int nt = bid & 7;
    int e = tile_expert[mt];
    if (e < 0) return;
    aBase = hmid + (size_t)mt * 64 * IDIM; K = IDIM;
    bBase = wb2 + ((size_t)e * HDIM + nt * 256) * IDIM;
    n0 = nt * 256;
    if (tid < 64) {
      int tk = row_token[mt * 64 + tid];
      if (tk < 0) { idx_s[tid] = -1; wgt_s[tid] = 0.f; }
      else {
        idx_s[tid] = ((long long)rowk[mt * 64 + tid] * NTOK + tk) * HDIM;
        wgt_s[tid] = rw[mt * 64 + tid];
      }
    }
  } else {
    int sb = bid - DN_NBLK_EXP;
    mt = sb >> 3; int nt = sb & 7;
    aBase = hs + (size_t)mt * 64 * ISDIM; K = ISDIM;
    bBase = wsdb + (size_t)(nt * 256) * ISDIM;
    n0 = nt * 256;
    if (tid < 64) {
      int t = mt * 64 + tid;
      idx_s[tid] = (2LL * NTOK + t) * (long long)HDIM;
      wgt_s[tid] = sig[t];
    }
  }
  int quad = lane >> 4, l16 = lane & 15, sw = l16 & 7;
  int lr = lane >> 3, lc = lane & 7;
  int swz = (lc ^ lr) * 8;
  const us* aSrc0 = aBase + (size_t)(w * 16 + lr) * K + swz;
  const us* aSrc1 = aBase + (size_t)(w * 16 + 8 + lr) * K + swz;
  size_t bLaneOff = (size_t)lr * K + swz;
  f32x4 acc[4][4] = {};
  for (int k0 = 0; k0 < K; k0 += 64) {
    glds16(aSrc0 + k0, As + (size_t)(w * 2) * 512);
    glds16(aSrc1 + k0, As + (size_t)(w * 2 + 1) * 512);
#pragma unroll
    for (int ii = 0; ii < 8; ii++) {
      int g = w * 8 + ii;  // 0..31
      glds16(bBase + (size_t)g * 8 * K + bLaneOff + k0, Bs + (size_t)g * 512);
    }
    __syncthreads();
#pragma unroll
    for (int ks = 0; ks < 2; ks++) {
      int cb = (ks * 4 + quad) ^ sw;
      bf16x8 af[4], bf[4];
#pragma unroll
      for (int ms = 0; ms < 4; ms++)
        af[ms] = *(const bf16x8*)&As[((ms * 16 + l16) * 8 + cb) * 8];
#pragma unroll
      for (int ns = 0; ns < 4; ns++) {
        int n = w * 64 + ns * 16 + l16;
        bf[ns] = *(const bf16x8*)&Bs[(n * 8 + cb) * 8];
      }
#pragma unroll
      for (int ms = 0; ms < 4; ms++)
#pragma unroll
        for (int ns = 0; ns < 4; ns++)
          acc[ms][ns] = __builtin_amdgcn_mfma_f32_16x16x32_bf16(af[ms], bf[ns], acc[ms][ns], 0, 0, 0);
    }
    __syncthreads();
  }
#pragma unroll
  for (int ms = 0; ms < 4; ms++)
#pragma unroll
    for (int r = 0; r < 4; r++) {
      int rr = ms * 16 + quad * 4 + r;
      long long ix = idx_s[rr];
      if (ix >= 0) {
        float wgt = wgt_s[rr];
        us* orow = slab + ix + n0 + w * 64;
#pragma unroll
        for (int ns = 0; ns < 4; ns++)
          orow[ns * 16 + l16] = f2bf(wgt * acc[ms][ns][r]);
      }
    }
}

// ------- kernel 5: out = slot0 + slot1 + sig*shared (streaming) -----------
__global__ __launch_bounds__(256) void k_combine(const us* __restrict__ slab,
                                                 float* __restrict__ out) {
  size_t i = ((size_t)blockIdx.x * 256 + threadIdx.x) * 8;
  bf16x8 a = *(const bf16x8*)(slab + i);
  bf16x8 b = *(const bf16x8*)(slab + (size_t)NTOK * HDIM + i);
  bf16x8 c = *(const bf16x8*)(slab + 2 * (size_t)NTOK * HDIM + i);
  float4 o[2];
#pragma unroll
  for (int j = 0; j < 8; j++) {
    float fa = __builtin_bit_cast(float, (unsigned)((unsigned)(us)a[j] << 16));
    float fb = __builtin_bit_cast(float, (unsigned)((unsigned)(us)b[j] << 16));
    float fc = __builtin_bit_cast(float, (unsigned)((unsigned)(us)c[j] << 16));
    ((float*)o)[j] = fa + fb + fc;
  }
  *(float4*)(out + i) = o[0];
  *(float4*)(out + i + 4) = o[1];
}

extern "C" void kernel_launch(void* const* d_in, const int* in_sizes, int n_in,
                              void* d_out, int out_size, void* d_ws, size_t ws_size,
                              hipStream_t stream) {
  const float* x = (const float*)d_in[0];
  const float* gate_w = (const float*)d_in[1];
  const float* w1 = (const float*)d_in[2];
  const float* w2 = (const float*)d_in[3];
  const float* w3 = (const float*)d_in[4];
  const float* wsg = (const float*)d_in[5];
  const float* wsu = (const float*)d_in[6];
  const float* wsd = (const float*)d_in[7];
  const float* sgw = (const float*)d_in[8];
  float* out = (float*)d_out;

  // workspace carve (16B aligned)
  us* xb = (us*)d_ws;                               // 4,194,304
  us* hs = xb + (size_t)NTOK * HDIM;                // 4,194,304
  us* hmid = hs + (size_t)NTOK * ISDIM;             // 2,621,440
  us* wb1 = hmid + (size_t)ROWSCAP * IDIM;          // 16,777,216
  us* wb3 = wb1 + (size_t)16777216;                 // 16,777,216
  us* wb2 = wb3 + (size_t)16777216;                 // 16,777,216
  us* wsgb = wb2 + (size_t)16777216;                // 4,194,304
  us* wsub = wsgb + (size_t)4194304;                // 4,194,304
  us* wsdb = wsub + (size_t)4194304;                // 4,194,304
  us* slab = wsdb + (size_t)4194304;                // 3 * 4,194,304
  float* rw = (float*)(slab + (size_t)3 * 4194304); // ROWSCAP
  float* wnorm = rw + ROWSCAP;                      // 4096
  float* sig = wnorm + 2 * NTOK;                    // 2048
  int* sel = (int*)(sig + NTOK);                    // 4096
  int* row_token = sel + 2 * NTOK;                  // ROWSCAP
  int* rowk = row_token + ROWSCAP;                  // ROWSCAP
  int* counts = rowk + ROWSCAP;                     // 16
  int* tile_expert = counts + NEXP;                 // 80

  SrcPtrs sp;
  sp.p[0] = w1; sp.p[1] = w3; sp.p[2] = w2;
  sp.p[3] = wsg; sp.p[4] = wsu; sp.p[5] = wsd;

  hipMemsetAsync(counts, 0, NEXP * sizeof(int), stream);
  k_convert<<<dim3(30720), dim3(256), 0, stream>>>(sp, wb1);
  k_router<<<dim3(NTOK / 4), dim3(256), 0, stream>>>(x, gate_w, sgw, xb, sel, wnorm,
                                                     sig, counts);
  k_scan_scatter<<<dim3(1), dim3(256), 0, stream>>>(counts, sel, wnorm, tile_expert,
                                                    row_token, rowk, rw);
  k_gu<<<dim3(GU_NBLK_EXP + GU_NBLK_SH), dim3(256), 0, stream>>>(
      xb, wb1, wb3, wsgb, wsub, tile_expert, row_token, hmid, hs);
  k_down<<<dim3(DN_NBLK_EXP + DN_NBLK_SH), dim3(256), 0, stream>>>(
      hmid, hs, wb2, wsdb, tile_expert, row_token, rowk, rw, sig, slab);
  k_combine<<<dim3(NTOK * HDIM / 2048), dim3(256), 0, stream>>>(slab, out);
}

// Round 5
// 459.851 us; speedup vs baseline: 1.1777x; 1.1155x over previous
//
#include <hip/hip_runtime.h>
#include <hip/hip_bf16.h>
#include <cmath>

#define HDIM 2048
#define NEXP 16
#define IDIM 512
#define ISDIM 2048
#define NTOK 2048
#define MAXT 48                 // 128-row expert tiles: 4096/128 + 16
#define ROWSCAP (MAXT * 128)    // 6144

#define GU_EXP (MAXT * 4)                    // 192 (IDIM/128 = 4 n-tiles)
#define GU_SH ((NTOK / 128) * (ISDIM / 128)) // 256
#define DN_SH ((NTOK / 128) * (HDIM / 256))  // 128
#define DN_EXP (MAXT * 8)                    // 384 (HDIM/256 = 8 n-tiles)

typedef short bf16x8 __attribute__((ext_vector_type(8)));
typedef float f32x4 __attribute__((ext_vector_type(4)));
typedef unsigned short us;
typedef __attribute__((address_space(1))) const unsigned int* as1p;
typedef __attribute__((address_space(3))) unsigned int* as3p;

__device__ __forceinline__ us f2bf(float f) {
  unsigned int u = __builtin_bit_cast(unsigned int, f);
  u += 0x7FFFu + ((u >> 16) & 1u);
  return (us)(u >> 16);
}
__device__ __forceinline__ float bf2f(us v) {
  return __builtin_bit_cast(float, (unsigned)v << 16);
}

// async 16B/lane global->LDS; global vaddr per-lane, LDS base wave-uniform
__device__ __forceinline__ void glds16(const void* g, void* l) {
  __builtin_amdgcn_global_load_lds((as1p)(unsigned long long)g,
                                   (as3p)(unsigned int)(unsigned long long)l, 16, 0, 0);
}

// load 8 fp32, round-half-up to bf16 (2 add + 1 perm per pair), 16B LDS write
__device__ __forceinline__ void stage_cvt(const float* __restrict__ src,
                                          us* __restrict__ dst) {
  const float4* p = (const float4*)src;
  float4 a = p[0], b = p[1];
  unsigned u0 = __builtin_bit_cast(unsigned, a.x) + 0x8000u;
  unsigned u1 = __builtin_bit_cast(unsigned, a.y) + 0x8000u;
  unsigned u2 = __builtin_bit_cast(unsigned, a.z) + 0x8000u;
  unsigned u3 = __builtin_bit_cast(unsigned, a.w) + 0x8000u;
  unsigned u4 = __builtin_bit_cast(unsigned, b.x) + 0x8000u;
  unsigned u5 = __builtin_bit_cast(unsigned, b.y) + 0x8000u;
  unsigned u6 = __builtin_bit_cast(unsigned, b.z) + 0x8000u;
  unsigned u7 = __builtin_bit_cast(unsigned, b.w) + 0x8000u;
  int4 v;
  v.x = __builtin_amdgcn_perm(u1, u0, 0x07060302);
  v.y = __builtin_amdgcn_perm(u3, u2, 0x07060302);
  v.z = __builtin_amdgcn_perm(u5, u4, 0x07060302);
  v.w = __builtin_amdgcn_perm(u7, u6, 0x07060302);
  *(int4*)dst = v;
}

// ------- kernel 1: router (wave per token) + x->bf16 conversion fused -----
__global__ __launch_bounds__(256) void k_router(const float* __restrict__ x,
                                                const float* __restrict__ gate_w,
                                                const float* __restrict__ sgw,
                                                us* __restrict__ xb,
                                                int* __restrict__ sel,
                                                float* __restrict__ wnorm,
                                                float* __restrict__ sig,
                                                int* __restrict__ counts) {
  __shared__ float lg[4][17];
  int tid = threadIdx.x, wid = tid >> 6, lane = tid & 63;
  int t = blockIdx.x * 4 + wid;
  const float4* xrow = reinterpret_cast<const float4*>(x + (size_t)t * HDIM);
  float4 xv[8];
#pragma unroll
  for (int s = 0; s < 8; s++) xv[s] = xrow[s * 64 + lane];
  ushort4* xbrow = reinterpret_cast<ushort4*>(xb + (size_t)t * HDIM);
#pragma unroll
  for (int s = 0; s < 8; s++) {
    ushort4 o;
    o.x = f2bf(xv[s].x); o.y = f2bf(xv[s].y); o.z = f2bf(xv[s].z); o.w = f2bf(xv[s].w);
    xbrow[s * 64 + lane] = o;
  }
#pragma unroll 1
  for (int e = 0; e < 17; e++) {
    const float4* gr =
        reinterpret_cast<const float4*>(e < 16 ? gate_w + (size_t)e * HDIM : sgw);
    float acc = 0.f;
#pragma unroll
    for (int s = 0; s < 8; s++) {
      float4 g = gr[s * 64 + lane];
      acc += xv[s].x * g.x + xv[s].y * g.y + xv[s].z * g.z + xv[s].w * g.w;
    }
#pragma unroll
    for (int off = 32; off; off >>= 1) acc += __shfl_xor(acc, off, 64);
    if (lane == 0) lg[wid][e] = acc;
  }
  if (lane == 0) {
    float* L = lg[wid];
    int i1 = 0; float v1 = L[0];
    for (int i = 1; i < NEXP; i++) if (L[i] > v1) { v1 = L[i]; i1 = i; }
    int i2 = (i1 == 0) ? 1 : 0; float v2 = L[i2];
    for (int i = 0; i < NEXP; i++)
      if (i != i1 && i != i2 && L[i] > v2) { v2 = L[i]; i2 = i; }
    float wa = 1.f / (1.f + expf(v2 - v1));  // renorm top-2 softmax
    sel[2 * t] = i1; sel[2 * t + 1] = i2;
    wnorm[2 * t] = wa; wnorm[2 * t + 1] = 1.f - wa;
    sig[t] = 1.f / (1.f + expf(-L[16]));
    atomicAdd(&counts[i1], 1);
    atomicAdd(&counts[i2], 1);
  }
}

// ------- kernel 2: scan + scatter (128-aligned offsets) -------------------
__global__ __launch_bounds__(256) void k_scan_scatter(const int* __restrict__ counts,
                                                      const int* __restrict__ sel,
                                                      const float* __restrict__ wnorm,
                                                      int* __restrict__ tile_expert,
                                                      int* __restrict__ row_token,
                                                      int* __restrict__ rowk,
                                                      float* __restrict__ rw) {
  __shared__ int offs_s[NEXP];
  __shared__ int fill_s[NEXP];
  int tid = threadIdx.x;
  for (int r = tid; r < ROWSCAP; r += 256) row_token[r] = -1;
  if (tid < NEXP) fill_s[tid] = 0;
  if (tid == 0) {
    int acc = 0;
    for (int e = 0; e < NEXP; e++) {
      offs_s[e] = acc;
      int nt = (counts[e] + 127) >> 7;
      for (int i = 0; i < nt; i++) tile_expert[(acc >> 7) + i] = e;
      acc += nt << 7;
    }
    for (int m = acc >> 7; m < MAXT; m++) tile_expert[m] = -1;
  }
  __syncthreads();
  for (int t = tid; t < NTOK; t += 256) {
    for (int k = 0; k < 2; k++) {
      int e = sel[2 * t + k];
      int pos = atomicAdd(&fill_s[e], 1);
      int row = offs_s[e] + pos;
      row_token[row] = t;
      rowk[row] = k;
      rw[row] = wnorm[2 * t + k];
    }
  }
}

// ------- kernel 3: gate/up GEMM, 128x128 tiles, 512 thr, in-kernel cvt ----
// waves 0-3: G matrix (2x2 of 64x64), waves 4-7: U. Epilogue joins via LDS.
__global__ __launch_bounds__(512) void k_gu(
    const us* __restrict__ xb, const float* __restrict__ w1,
    const float* __restrict__ w3, const float* __restrict__ wsg,
    const float* __restrict__ wsu, const int* __restrict__ tile_expert,
    const int* __restrict__ row_token, us* __restrict__ hmid,
    us* __restrict__ hs) {
  __shared__ us As[128 * 64];      // 16KB
  __shared__ us Bs[2][128 * 64];   // 32KB (G,U); reused as 128x128 U-buf in epilogue
  __shared__ int toks_s[128];
  int bid = blockIdx.x, tid = threadIdx.x;
  int w = tid >> 6, lane = tid & 63;
  const float *bG, *bU;
  us* outp;
  int mt, n0, ostride;
  if (bid < GU_EXP) {
    mt = bid >> 2; int nt = bid & 3;
    int e = tile_expert[mt];
    if (e < 0) return;
    if (tid < 128) {
      int tk = row_token[mt * 128 + tid];
      toks_s[tid] = tk < 0 ? 0 : tk;
    }
    bG = w1 + ((size_t)e * IDIM + nt * 128) * HDIM;
    bU = w3 + ((size_t)e * IDIM + nt * 128) * HDIM;
    outp = hmid; ostride = IDIM; n0 = nt * 128;
  } else {
    int sb = bid - GU_EXP;
    mt = sb >> 4; int nt = sb & 15;
    if (tid < 128) toks_s[tid] = mt * 128 + tid;
    bG = wsg + (size_t)(nt * 128) * HDIM;
    bU = wsu + (size_t)(nt * 128) * HDIM;
    outp = hs; ostride = ISDIM; n0 = nt * 128;
  }
  __syncthreads();
  int lr = lane >> 3, lc = lane & 7;
  int swz = (lc ^ lr) * 8;
  const us* aSrc0 = xb + (size_t)toks_s[w * 16 + lr] * HDIM + swz;
  const us* aSrc1 = xb + (size_t)toks_s[w * 16 + 8 + lr] * HDIM + swz;
  // B staging slots: 2 per matrix per thread (slot = row*8+pc, 128 rows)
  int r0 = tid >> 3, p0 = tid & 7, g0 = p0 ^ (r0 & 7);
  int r1 = (tid + 512) >> 3, g1 = p0 ^ (r1 & 7);
  size_t bo0 = (size_t)r0 * HDIM + g0 * 8;
  size_t bo1 = (size_t)r1 * HDIM + g1 * 8;
  int mat = w >> 2, sub = w & 3, wm = sub >> 1, wn = sub & 1;
  int quad = lane >> 4, l16 = lane & 15, sw = l16 & 7;
  f32x4 acc[4][4] = {};
  for (int k0 = 0; k0 < HDIM; k0 += 64) {
    glds16(aSrc0 + k0, As + w * 1024);
    glds16(aSrc1 + k0, As + w * 1024 + 512);
    stage_cvt(bG + bo0 + k0, &Bs[0][(r0 * 8 + p0) * 8]);
    stage_cvt(bG + bo1 + k0, &Bs[0][(r1 * 8 + p0) * 8]);
    stage_cvt(bU + bo0 + k0, &Bs[1][(r0 * 8 + p0) * 8]);
    stage_cvt(bU + bo1 + k0, &Bs[1][(r1 * 8 + p0) * 8]);
    __syncthreads();
#pragma unroll
    for (int ks = 0; ks < 2; ks++) {
      int cb = (ks * 4 + quad) ^ sw;
      bf16x8 af[4], bf[4];
#pragma unroll
      for (int ms = 0; ms < 4; ms++)
        af[ms] = *(const bf16x8*)&As[((wm * 64 + ms * 16 + l16) * 8 + cb) * 8];
#pragma unroll
      for (int ns = 0; ns < 4; ns++)
        bf[ns] = *(const bf16x8*)&Bs[mat][((wn * 64 + ns * 16 + l16) * 8 + cb) * 8];
#pragma unroll
      for (int ms = 0; ms < 4; ms++)
#pragma unroll
        for (int ns = 0; ns < 4; ns++)
          acc[ms][ns] = __builtin_amdgcn_mfma_f32_16x16x32_bf16(af[ms], bf[ns], acc[ms][ns], 0, 0, 0);
    }
    __syncthreads();
  }
  // epilogue: U waves park u (bf16) in LDS; G waves do silu(g)*u -> store
  us* ub = (us*)Bs;
  if (mat == 1) {
#pragma unroll
    for (int ms = 0; ms < 4; ms++)
#pragma unroll
      for (int ns = 0; ns < 4; ns++)
#pragma unroll
        for (int r = 0; r < 4; r++) {
          int row = wm * 64 + ms * 16 + quad * 4 + r;
          int col = wn * 64 + ns * 16 + l16;
          ub[row * 128 + col] = f2bf(acc[ms][ns][r]);
        }
  }
  __syncthreads();
  if (mat == 0) {
#pragma unroll
    for (int ms = 0; ms < 4; ms++)
#pragma unroll
      for (int ns = 0; ns < 4; ns++)
#pragma unroll
        for (int r = 0; r < 4; r++) {
          int row = wm * 64 + ms * 16 + quad * 4 + r;
          int col = wn * 64 + ns * 16 + l16;
          float g = acc[ms][ns][r];
          float u = bf2f(ub[row * 128 + col]);
          float hv = (g / (1.f + __expf(-g))) * u;
          outp[(size_t)(mt * 128 + row) * ostride + n0 + col] = f2bf(hv);
        }
  }
}

// ------- kernel 4: down GEMMs 128x256, weighted bf16 stores into slabs ----
__global__ __launch_bounds__(512) void k_down(
    const us* __restrict__ hmid, const us* __restrict__ hs,
    const float* __restrict__ w2, const float* __restrict__ wsd,
    const int* __restrict__ tile_expert, const int* __restrict__ row_token,
    const int* __restrict__ rowk, const float* __restrict__ rw,
    const float* __restrict__ sig, us* __restrict__ slab) {
  __shared__ us As[128 * 64];   // 16KB
  __shared__ us Bs[256 * 64];   // 32KB
  __shared__ int idx_s[128];
  __shared__ float wgt_s[128];
  int bid = blockIdx.x, tid = threadIdx.x;
  int w = tid >> 6, lane = tid & 63;
  const us* aBase;
  const float* bBase;
  int K, mt, n0;
  if (bid < DN_SH) {  // shared expert first (K=2048, longest)
    mt = bid >> 3; int nt = bid & 7;
    aBase = hs + (size_t)mt * 128 * ISDIM; K = ISDIM;
    bBase = wsd + (size_t)(nt * 256) * ISDIM;
    n0 = nt * 256;
    if (tid < 128) {
      int t = mt * 128 + tid;
      idx_s[tid] = 2 * NTOK * HDIM + t * HDIM;
      wgt_s[tid] = sig[t];
    }
  } else {
    int sb = bid - DN_SH;
    mt = sb >> 3; int nt = sb & 7;
    int e = tile_expert[mt];
    if (e < 0) return;
    aBase = hmid + (size_t)mt * 128 * IDIM; K = IDIM;
    bBase = w2 + ((size_t)e * HDIM + nt * 256) * IDIM;
    n0 = nt * 256;
    if (tid < 128) {
      int tk = row_token[mt * 128 + tid];
      if (tk < 0) { idx_s[tid] = -1; wgt_s[tid] = 0.f; }
      else {
        idx_s[tid] = (rowk[mt * 128 + tid] * NTOK + tk) * HDIM;
        wgt_s[tid] = rw[mt * 128 + tid];
      }
    }
  }
  __syncthreads();
  int lr = lane >> 3, lc = lane & 7;
  int swz = (lc ^ lr) * 8;
  const us* aSrc0 = aBase + (size_t)(w * 16 + lr) * K + swz;
  const us* aSrc1 = aBase + (size_t)(w * 16 + 8 + lr) * K + swz;
  // B staging: 4 slots/thread over 256 rows x 8 chunks
  int r0 = tid >> 3, p0 = tid & 7;
  int wmn = w >> 2, wn = w & 3;  // waves 2(m) x 4(n)
  int quad = lane >> 4, l16 = lane & 15, sw = l16 & 7;
  f32x4 acc[4][4] = {};
  for (int k0 = 0; k0 < K; k0 += 64) {
    glds16(aSrc0 + k0, As + w * 1024);
    glds16(aSrc1 + k0, As + w * 1024 + 512);
#pragma unroll
    for (int j = 0; j < 4; j++) {
      int row = r0 + j * 64;
      int gc = p0 ^ (row & 7);
      stage_cvt(bBase + (size_t)row * K + gc * 8 + k0, &Bs[(row * 8 + p0) * 8]);
    }
    __syncthreads();
#pragma unroll
    for (int ks = 0; ks < 2; ks++) {
      int cb = (ks * 4 + quad) ^ sw;
      bf16x8 af[4], bf[4];
#pragma unroll
      for (int ms = 0; ms < 4; ms++)
        af[ms] = *(const bf16x8*)&As[((wmn * 64 + ms * 16 + l16) * 8 + cb) * 8];
#pragma unroll
      for (int ns = 0; ns < 4; ns++)
        bf[ns] = *(const bf16x8*)&Bs[((wn * 64 + ns * 16 + l16) * 8 + cb) * 8];
#pragma unroll
      for (int ms = 0; ms < 4; ms++)
#pragma unroll
        for (int ns = 0; ns < 4; ns++)
          acc[ms][ns] = __builtin_amdgcn_mfma_f32_16x16x32_bf16(af[ms], bf[ns], acc[ms][ns], 0, 0, 0);
    }
    __syncthreads();
  }
#pragma unroll
  for (int ms = 0; ms < 4; ms++)
#pragma unroll
    for (int r = 0; r < 4; r++) {
      int rr = wmn * 64 + ms * 16 + quad * 4 + r;
      int ix = idx_s[rr];
      if (ix >= 0) {
        float wgt = wgt_s[rr];
        us* orow = slab + (size_t)ix + n0 + wn * 64;
#pragma unroll
        for (int ns = 0; ns < 4; ns++)
          orow[ns * 16 + l16] = f2bf(wgt * acc[ms][ns][r]);
      }
    }
}

// ------- kernel 5: out = slot0 + slot1 + sig*shared (streaming) -----------
__global__ __launch_bounds__(256) void k_combine(const us* __restrict__ slab,
                                                 float* __restrict__ out) {
  size_t i = ((size_t)blockIdx.x * 256 + threadIdx.x) * 8;
  bf16x8 a = *(const bf16x8*)(slab + i);
  bf16x8 b = *(const bf16x8*)(slab + (size_t)NTOK * HDIM + i);
  bf16x8 c = *(const bf16x8*)(slab + 2 * (size_t)NTOK * HDIM + i);
  float4 o[2];
#pragma unroll
  for (int j = 0; j < 8; j++)
    ((float*)o)[j] = bf2f((us)a[j]) + bf2f((us)b[j]) + bf2f((us)c[j]);
  *(float4*)(out + i) = o[0];
  *(float4*)(out + i + 4) = o[1];
}

extern "C" void kernel_launch(void* const* d_in, const int* in_sizes, int n_in,
                              void* d_out, int out_size, void* d_ws, size_t ws_size,
                              hipStream_t stream) {
  const float* x = (const float*)d_in[0];
  const float* gate_w = (const float*)d_in[1];
  const float* w1 = (const float*)d_in[2];
  const float* w2 = (const float*)d_in[3];
  const float* w3 = (const float*)d_in[4];
  const float* wsg = (const float*)d_in[5];
  const float* wsu = (const float*)d_in[6];
  const float* wsd = (const float*)d_in[7];
  const float* sgw = (const float*)d_in[8];
  float* out = (float*)d_out;

  // workspace carve (16B aligned)
  us* xb = (us*)d_ws;                               // NTOK*HDIM
  us* hs = xb + (size_t)NTOK * HDIM;                // NTOK*ISDIM
  us* hmid = hs + (size_t)NTOK * ISDIM;             // ROWSCAP*IDIM
  us* slab = hmid + (size_t)ROWSCAP * IDIM;         // 3*NTOK*HDIM
  float* rw = (float*)(slab + (size_t)3 * NTOK * HDIM);  // ROWSCAP
  float* wnorm = rw + ROWSCAP;                      // 4096
  float* sig = wnorm + 2 * NTOK;                    // 2048
  int* sel = (int*)(sig + NTOK);                    // 4096
  int* row_token = sel + 2 * NTOK;                  // ROWSCAP
  int* rowk = row_token + ROWSCAP;                  // ROWSCAP
  int* counts = rowk + ROWSCAP;                     // 16
  int* tile_expert = counts + NEXP;                 // MAXT

  hipMemsetAsync(counts, 0, NEXP * sizeof(int), stream);
  k_router<<<dim3(NTOK / 4), dim3(256), 0, stream>>>(x, gate_w, sgw, xb, sel, wnorm,
                                                     sig, counts);
  k_scan_scatter<<<dim3(1), dim3(256), 0, stream>>>(counts, sel, wnorm, tile_expert,
                                                    row_token, rowk, rw);
  k_gu<<<dim3(GU_EXP + GU_SH), dim3(512), 0, stream>>>(
      xb, w1, w3, wsg, wsu, tile_expert, row_token, hmid, hs);
  k_down<<<dim3(DN_SH + DN_EXP), dim3(512), 0, stream>>>(
      hmid, hs, w2, wsd, tile_expert, row_token, rowk, rw, sig, slab);
  k_combine<<<dim3(NTOK * HDIM / 2048), dim3(256), 0, stream>>>(slab, out);
}